// Round 1
// baseline (172.280 us; speedup 1.0000x reference)
//
#include <hip/hip_runtime.h>
#include <stdint.h>

#define B_ 4
#define T_ 2048
#define F_ 512
#define H_ 8
#define DK_ 64
#define BT_ (B_*T_)   // 8192

typedef short bf16x8 __attribute__((ext_vector_type(8)));
typedef float f32x4 __attribute__((ext_vector_type(4)));

__device__ __forceinline__ unsigned short f2bf(float f) {
  union { float f; unsigned u; } v; v.f = f;
  return (unsigned short)((v.u + 0x7fffu + ((v.u >> 16) & 1u)) >> 16);
}

__device__ __forceinline__ void gload_lds16(const void* g, void* l) {
  __builtin_amdgcn_global_load_lds((const __attribute__((address_space(1))) void*)g,
                                   (__attribute__((address_space(3))) void*)l, 16, 0, 0);
}

// ---------------- weight conversion fp32 -> bf16 ----------------
__global__ void convert_w(const float* __restrict__ wq, const float* __restrict__ wk,
                          const float* __restrict__ wv, const float* __restrict__ wo,
                          unsigned short* __restrict__ dst) {
  const int seg = blockIdx.y;
  const float* src = seg == 0 ? wq : (seg == 1 ? wk : (seg == 2 ? wv : wo));
  unsigned short* out = dst + (size_t)seg * F_ * F_;
  const int idx = (blockIdx.x * 256 + threadIdx.x) * 8;   // 128 blocks * 256 * 8 = 262144 exact
  float4 a = *(const float4*)(src + idx);
  float4 b = *(const float4*)(src + idx + 4);
  union { unsigned short u[8]; bf16x8 v; } t;
  t.u[0] = f2bf(a.x); t.u[1] = f2bf(a.y); t.u[2] = f2bf(a.z); t.u[3] = f2bf(a.w);
  t.u[4] = f2bf(b.x); t.u[5] = f2bf(b.y); t.u[6] = f2bf(b.z); t.u[7] = f2bf(b.w);
  *(bf16x8*)(out + idx) = t.v;
}

// ---------------- GEMM: C = A @ W^T + bias ----------------
// A: [M=8192][K=512]  (fp32 from d_in, or bf16 from ws)
// W: [N=512][K=512] bf16 (row n holds W[n][k] -> B^T-friendly layout)
// 128x128 tile, 4 waves (2x2), BK=32, 16x16x32 bf16 MFMA  (m97 structure)
template <bool A_F32, bool OUT_F32>
__global__ __launch_bounds__(256, 2) void gemm_bt(
    const float* __restrict__ af0, const float* __restrict__ af1, const float* __restrict__ af2,
    const unsigned short* __restrict__ Abf,
    const unsigned short* __restrict__ Wbase,
    const float* __restrict__ b0, const float* __restrict__ b1, const float* __restrict__ b2,
    unsigned short* __restrict__ outb, float* __restrict__ outf) {
  const int p = blockIdx.z;
  const float* Af = (p == 0) ? af0 : (p == 1 ? af1 : af2);
  const unsigned short* W = Wbase + (size_t)p * F_ * F_;
  const float* bias = (p == 0) ? b0 : (p == 1 ? b1 : b2);

  const int tid = threadIdx.x;
  const int wid = tid >> 6, lane = tid & 63;
  const int lr = lane & 15, lg = lane >> 4;
  const int wr = wid >> 1, wc = wid & 1;
  const int m0 = blockIdx.x * 128, n0 = blockIdx.y * 128;

  __shared__ __align__(16) unsigned short As[128 * 32];
  __shared__ __align__(16) unsigned short Bs[128 * 32];

  f32x4 acc[4][4] = {};

  for (int k0 = 0; k0 < F_; k0 += 32) {
#pragma unroll
    for (int i = 0; i < 2; ++i) {
      const int ch = i * 256 + tid;
      const int r = ch >> 2, s = ch & 3;
      if constexpr (A_F32) {
        const float* src = Af + (size_t)(m0 + r) * F_ + k0 + s * 8;
        float4 x0 = *(const float4*)src;
        float4 x1 = *(const float4*)(src + 4);
        union { unsigned short u[8]; bf16x8 v; } t;
        t.u[0] = f2bf(x0.x); t.u[1] = f2bf(x0.y); t.u[2] = f2bf(x0.z); t.u[3] = f2bf(x0.w);
        t.u[4] = f2bf(x1.x); t.u[5] = f2bf(x1.y); t.u[6] = f2bf(x1.z); t.u[7] = f2bf(x1.w);
        *(bf16x8*)&As[ch * 8] = t.v;
      } else {
        gload_lds16(Abf + (size_t)(m0 + r) * F_ + k0 + s * 8, &As[(i * 256 + wid * 64) * 8]);
      }
      gload_lds16(W + (size_t)(n0 + r) * F_ + k0 + s * 8, &Bs[(i * 256 + wid * 64) * 8]);
    }
    __syncthreads();

    bf16x8 af[4], bf[4];
#pragma unroll
    for (int m = 0; m < 4; ++m)
      af[m] = *(const bf16x8*)&As[(wr * 64 + m * 16 + lr) * 32 + lg * 8];
#pragma unroll
    for (int n = 0; n < 4; ++n)
      bf[n] = *(const bf16x8*)&Bs[(wc * 64 + n * 16 + lr) * 32 + lg * 8];
#pragma unroll
    for (int m = 0; m < 4; ++m)
#pragma unroll
      for (int n = 0; n < 4; ++n)
        acc[m][n] = __builtin_amdgcn_mfma_f32_16x16x32_bf16(af[m], bf[n], acc[m][n], 0, 0, 0);
    __syncthreads();
  }

  unsigned short* ob = OUT_F32 ? nullptr : outb + (size_t)p * BT_ * F_;
#pragma unroll
  for (int n = 0; n < 4; ++n) {
    const int col = n0 + wc * 64 + n * 16 + lr;
    const float bv = bias[col];
#pragma unroll
    for (int m = 0; m < 4; ++m) {
      const int rbase = m0 + wr * 64 + m * 16 + lg * 4;
#pragma unroll
      for (int j = 0; j < 4; ++j) {
        const float v = acc[m][n][j] + bv;
        if constexpr (OUT_F32) outf[(size_t)(rbase + j) * F_ + col] = v;
        else                   ob[(size_t)(rbase + j) * F_ + col] = f2bf(v);
      }
    }
  }
}

// ---------------- V transpose: (B,T,F)-per-head -> [BH][DK][T] ----------------
__global__ void transpose_v(const unsigned short* __restrict__ Vp, unsigned short* __restrict__ Vt) {
  const int bh = blockIdx.y, b = bh >> 3, h = bh & 7;
  const int t0 = blockIdx.x * 64;
  const int tid = threadIdx.x;
  __shared__ __align__(16) unsigned short tile[64][72];

#pragma unroll
  for (int i = 0; i < 2; ++i) {
    const int ch = i * 256 + tid;          // 512 chunks of 8
    const int t = ch >> 3, s = ch & 7;
    bf16x8 v = *(const bf16x8*)(Vp + (size_t)(b * T_ + t0 + t) * F_ + h * DK_ + s * 8);
    *(bf16x8*)&tile[t][s * 8] = v;
  }
  __syncthreads();
#pragma unroll
  for (int i = 0; i < 2; ++i) {
    const int ch = i * 256 + tid;
    const int d = ch >> 3, s = ch & 7;
    union { unsigned short u[8]; bf16x8 v; } r;
#pragma unroll
    for (int j = 0; j < 8; ++j) r.u[j] = tile[s * 8 + j][d];
    *(bf16x8*)(Vt + ((size_t)bh * DK_ + d) * T_ + t0 + s * 8) = r.v;
  }
}

// ---------------- flash attention ----------------
// block: 128 q-rows (4 waves x 32), KV tile = 64. K/Vt staged in swizzled LDS.
__global__ __launch_bounds__(256, 2) void attn_kernel(
    const unsigned short* __restrict__ Qp,
    const unsigned short* __restrict__ Kp,
    const unsigned short* __restrict__ Vt,
    const int* __restrict__ mask,
    unsigned short* __restrict__ X) {
  const int tid = threadIdx.x, wid = tid >> 6, lane = tid & 63;
  const int lr = lane & 15, lg = lane >> 4;
  const int bh = blockIdx.y, b = bh >> 3, h = bh & 7;
  const int q0 = blockIdx.x * 128;
  const int wq0 = q0 + wid * 32;

  __shared__ __align__(16) unsigned short Ks[64 * 64];   // [kvcol][dk], 16B-slot XOR swizzle
  __shared__ __align__(16) unsigned short Vs[64 * 64];   // [d][k], swizzled
  __shared__ __align__(16) unsigned short Ps[4][32 * 64];// per-wave P, swizzled

  // Q fragments held in registers for the whole block
  bf16x8 qf[2][2];
#pragma unroll
  for (int m = 0; m < 2; ++m)
#pragma unroll
    for (int kk = 0; kk < 2; ++kk)
      qf[m][kk] = *(const bf16x8*)(Qp + (size_t)(b * T_ + wq0 + m * 16 + lr) * F_ + h * DK_ + kk * 32 + lg * 8);

  float mrun[2][4], lrun[2][4];
  f32x4 ao[2][4] = {};
#pragma unroll
  for (int m = 0; m < 2; ++m)
#pragma unroll
    for (int j = 0; j < 4; ++j) { mrun[m][j] = -1e30f; lrun[m][j] = 0.0f; }

  for (int kv0 = 0; kv0 < T_; kv0 += 64) {
    // stage K tile [64][64] and Vt tile [64][64]; inverse-swizzled global source
#pragma unroll
    for (int i = 0; i < 2; ++i) {
      const int ch = i * 256 + tid;
      const int r = ch >> 3, s = ch & 7;
      gload_lds16(Kp + (size_t)(b * T_ + kv0 + r) * F_ + h * DK_ + ((s ^ (r & 7)) * 8),
                  &Ks[(i * 256 + wid * 64) * 8]);
      gload_lds16(Vt + ((size_t)bh * DK_ + r) * T_ + kv0 + ((s ^ (r & 7)) * 8),
                  &Vs[(i * 256 + wid * 64) * 8]);
    }
    __syncthreads();

    // S = Q K^T
    f32x4 sf[2][4] = {};
#pragma unroll
    for (int n = 0; n < 4; ++n) {
      const int col = n * 16 + lr;
#pragma unroll
      for (int ks = 0; ks < 2; ++ks) {
        bf16x8 kf = *(const bf16x8*)&Ks[col * 64 + ((((ks << 2) | lg) ^ (col & 7)) * 8)];
        sf[0][n] = __builtin_amdgcn_mfma_f32_16x16x32_bf16(qf[0][ks], kf, sf[0][n], 0, 0, 0);
        sf[1][n] = __builtin_amdgcn_mfma_f32_16x16x32_bf16(qf[1][ks], kf, sf[1][n], 0, 0, 0);
      }
    }

    int mk[4];
#pragma unroll
    for (int n = 0; n < 4; ++n) mk[n] = mask[b * T_ + kv0 + n * 16 + lr];

    // scale + mask + row max
    float rmx[2][4];
#pragma unroll
    for (int m = 0; m < 2; ++m)
#pragma unroll
      for (int j = 0; j < 4; ++j) {
        float mx = -__builtin_inff();
#pragma unroll
        for (int n = 0; n < 4; ++n) {
          float s = sf[m][n][j] * 0.125f;
          s = mk[n] ? s : -__builtin_inff();
          sf[m][n][j] = s;
          mx = fmaxf(mx, s);
        }
        rmx[m][j] = mx;
      }
#pragma unroll
    for (int m = 0; m < 2; ++m)
#pragma unroll
      for (int j = 0; j < 4; ++j)
#pragma unroll
        for (int d = 1; d < 16; d <<= 1)
          rmx[m][j] = fmaxf(rmx[m][j], __shfl_xor(rmx[m][j], d, 64));

    float alpha[2][4], rsum[2][4];
#pragma unroll
    for (int m = 0; m < 2; ++m)
#pragma unroll
      for (int j = 0; j < 4; ++j) {
        const float mnew = fmaxf(mrun[m][j], rmx[m][j]);   // >= -1e30, always finite
        alpha[m][j] = __expf(mrun[m][j] - mnew);
        mrun[m][j] = mnew;
        float rs = 0.0f;
#pragma unroll
        for (int n = 0; n < 4; ++n) {
          const float pv = __expf(sf[m][n][j] - mnew);     // -inf -> 0
          sf[m][n][j] = pv;
          rs += pv;
        }
        rsum[m][j] = rs;
      }
#pragma unroll
    for (int m = 0; m < 2; ++m)
#pragma unroll
      for (int j = 0; j < 4; ++j) {
#pragma unroll
        for (int d = 1; d < 16; d <<= 1) rsum[m][j] += __shfl_xor(rsum[m][j], d, 64);
        lrun[m][j] = lrun[m][j] * alpha[m][j] + rsum[m][j];
      }
    // rescale O
#pragma unroll
    for (int m = 0; m < 2; ++m)
#pragma unroll
      for (int nd = 0; nd < 4; ++nd)
#pragma unroll
        for (int j = 0; j < 4; ++j) ao[m][nd][j] *= alpha[m][j];

    // P -> per-wave LDS (bf16, swizzled) to re-layout into MFMA A-fragments
#pragma unroll
    for (int m = 0; m < 2; ++m)
#pragma unroll
      for (int n = 0; n < 4; ++n)
#pragma unroll
        for (int j = 0; j < 4; ++j) {
          const int r = m * 16 + lg * 4 + j;
          const int c = n * 16 + lr;
          Ps[wid][r * 64 + (((c >> 3) ^ (r & 7)) * 8) + (c & 7)] = f2bf(sf[m][n][j]);
        }
    asm volatile("s_waitcnt lgkmcnt(0)" ::: "memory");

    bf16x8 pf[2][2];
#pragma unroll
    for (int m = 0; m < 2; ++m)
#pragma unroll
      for (int ks = 0; ks < 2; ++ks) {
        const int r = m * 16 + lr;
        pf[m][ks] = *(const bf16x8*)&Ps[wid][r * 64 + ((((ks << 2) | lg) ^ (r & 7)) * 8)];
      }

    // O += P V
#pragma unroll
    for (int nd = 0; nd < 4; ++nd) {
      const int d = nd * 16 + lr;
#pragma unroll
      for (int ks = 0; ks < 2; ++ks) {
        bf16x8 vf = *(const bf16x8*)&Vs[d * 64 + ((((ks << 2) | lg) ^ (d & 7)) * 8)];
        ao[0][nd] = __builtin_amdgcn_mfma_f32_16x16x32_bf16(pf[0][ks], vf, ao[0][nd], 0, 0, 0);
        ao[1][nd] = __builtin_amdgcn_mfma_f32_16x16x32_bf16(pf[1][ks], vf, ao[1][nd], 0, 0, 0);
      }
    }
    __syncthreads();
  }

  // write X (bf16, (B,T,F) layout)
#pragma unroll
  for (int m = 0; m < 2; ++m)
#pragma unroll
    for (int nd = 0; nd < 4; ++nd)
#pragma unroll
      for (int j = 0; j < 4; ++j) {
        const int row = wq0 + m * 16 + lg * 4 + j;
        const int col = h * DK_ + nd * 16 + lr;
        X[(size_t)(b * T_ + row) * F_ + col] = f2bf(ao[m][nd][j] / lrun[m][j]);
      }
}

// ---------------- launcher ----------------
extern "C" void kernel_launch(void* const* d_in, const int* in_sizes, int n_in,
                              void* d_out, int out_size, void* d_ws, size_t ws_size,
                              hipStream_t stream) {
  const float* q  = (const float*)d_in[0];
  const float* k  = (const float*)d_in[1];
  const float* v  = (const float*)d_in[2];
  const int* mask = (const int*)d_in[3];
  const float* Wq = (const float*)d_in[4];
  const float* bq = (const float*)d_in[5];
  const float* Wk = (const float*)d_in[6];
  const float* bk = (const float*)d_in[7];
  const float* Wv = (const float*)d_in[8];
  const float* bv = (const float*)d_in[9];
  const float* Wo = (const float*)d_in[10];
  const float* bo = (const float*)d_in[11];
  float* out = (float*)d_out;

  unsigned short* ws = (unsigned short*)d_ws;
  unsigned short* wts  = ws;                               // 4*F*F           = 1,048,576
  unsigned short* proj = wts + (size_t)4 * F_ * F_;        // 3*BT*F (Q,K,V)  = 12,582,912
  unsigned short* vt   = proj + (size_t)3 * BT_ * F_;      // BT*F            = 4,194,304
  unsigned short* xbuf = vt + (size_t)BT_ * F_;            // BT*F            = 4,194,304
  // total 22,020,096 ushorts = 44 MB of d_ws

  convert_w<<<dim3(128, 4, 1), 256, 0, stream>>>(Wq, Wk, Wv, Wo, wts);
  gemm_bt<true, false><<<dim3(64, 4, 3), 256, 0, stream>>>(
      q, k, v, nullptr, wts, bq, bk, bv, proj, nullptr);
  transpose_v<<<dim3(32, 32, 1), 256, 0, stream>>>(proj + (size_t)2 * BT_ * F_, vt);
  attn_kernel<<<dim3(16, 32, 1), 256, 0, stream>>>(
      proj, proj + (size_t)BT_ * F_, vt, mask, xbuf);
  gemm_bt<false, true><<<dim3(64, 4, 1), 256, 0, stream>>>(
      nullptr, nullptr, nullptr, xbuf, wts + (size_t)3 * F_ * F_, bo, bo, bo, nullptr, out);
}

// Round 2
// 161.874 us; speedup vs baseline: 1.0643x; 1.0643x over previous
//
#include <hip/hip_runtime.h>
#include <stdint.h>

#define B_ 4
#define T_ 2048
#define F_ 512
#define H_ 8
#define DK_ 64
#define BT_ (B_*T_)   // 8192

typedef short bf16x8 __attribute__((ext_vector_type(8)));
typedef float f32x4 __attribute__((ext_vector_type(4)));

__device__ __forceinline__ unsigned short f2bf(float f) {
  union { float f; unsigned u; } v; v.f = f;
  return (unsigned short)((v.u + 0x7fffu + ((v.u >> 16) & 1u)) >> 16);
}

__device__ __forceinline__ void gload_lds16(const void* g, void* l) {
  __builtin_amdgcn_global_load_lds((const __attribute__((address_space(1))) void*)g,
                                   (__attribute__((address_space(3))) void*)l, 16, 0, 0);
}

// ---------------- weight conversion fp32 -> bf16, plus mask -> float addend ----------------
__global__ void convert_w(const float* __restrict__ wq, const float* __restrict__ wk,
                          const float* __restrict__ wv, const float* __restrict__ wo,
                          const int* __restrict__ mask,
                          unsigned short* __restrict__ dst, float* __restrict__ maskf) {
  const int seg = blockIdx.y;
  if (seg == 4) {
    if (blockIdx.x < 4) {   // 4 blocks * 256 * 8 = 8192 = B*T exact
      const int idx = (blockIdx.x * 256 + threadIdx.x) * 8;
      int4 a = *(const int4*)(mask + idx);
      int4 b = *(const int4*)(mask + idx + 4);
      float4 fa, fb;
      fa.x = a.x ? 0.0f : -__builtin_inff(); fa.y = a.y ? 0.0f : -__builtin_inff();
      fa.z = a.z ? 0.0f : -__builtin_inff(); fa.w = a.w ? 0.0f : -__builtin_inff();
      fb.x = b.x ? 0.0f : -__builtin_inff(); fb.y = b.y ? 0.0f : -__builtin_inff();
      fb.z = b.z ? 0.0f : -__builtin_inff(); fb.w = b.w ? 0.0f : -__builtin_inff();
      *(float4*)(maskf + idx) = fa;
      *(float4*)(maskf + idx + 4) = fb;
    }
    return;
  }
  const float* src = seg == 0 ? wq : (seg == 1 ? wk : (seg == 2 ? wv : wo));
  unsigned short* out = dst + (size_t)seg * F_ * F_;
  const int idx = (blockIdx.x * 256 + threadIdx.x) * 8;   // 128 blocks * 256 * 8 = 262144 exact
  float4 a = *(const float4*)(src + idx);
  float4 b = *(const float4*)(src + idx + 4);
  union { unsigned short u[8]; bf16x8 v; } t;
  t.u[0] = f2bf(a.x); t.u[1] = f2bf(a.y); t.u[2] = f2bf(a.z); t.u[3] = f2bf(a.w);
  t.u[4] = f2bf(b.x); t.u[5] = f2bf(b.y); t.u[6] = f2bf(b.z); t.u[7] = f2bf(b.w);
  *(bf16x8*)(out + idx) = t.v;
}

// ---------------- GEMM: C = A @ W^T + bias ----------------
template <bool A_F32, bool OUT_F32>
__global__ __launch_bounds__(256, 2) void gemm_bt(
    const float* __restrict__ af0, const float* __restrict__ af1, const float* __restrict__ af2,
    const unsigned short* __restrict__ Abf,
    const unsigned short* __restrict__ Wbase,
    const float* __restrict__ b0, const float* __restrict__ b1, const float* __restrict__ b2,
    unsigned short* __restrict__ outb, float* __restrict__ outf) {
  const int p = blockIdx.z;
  const float* Af = (p == 0) ? af0 : (p == 1 ? af1 : af2);
  const unsigned short* W = Wbase + (size_t)p * F_ * F_;
  const float* bias = (p == 0) ? b0 : (p == 1 ? b1 : b2);

  const int tid = threadIdx.x;
  const int wid = tid >> 6, lane = tid & 63;
  const int lr = lane & 15, lg = lane >> 4;
  const int wr = wid >> 1, wc = wid & 1;
  const int m0 = blockIdx.x * 128, n0 = blockIdx.y * 128;

  __shared__ __align__(16) unsigned short As[128 * 32];
  __shared__ __align__(16) unsigned short Bs[128 * 32];

  f32x4 acc[4][4] = {};

  for (int k0 = 0; k0 < F_; k0 += 32) {
#pragma unroll
    for (int i = 0; i < 2; ++i) {
      const int ch = i * 256 + tid;
      const int r = ch >> 2, s = ch & 3;
      if constexpr (A_F32) {
        const float* src = Af + (size_t)(m0 + r) * F_ + k0 + s * 8;
        float4 x0 = *(const float4*)src;
        float4 x1 = *(const float4*)(src + 4);
        union { unsigned short u[8]; bf16x8 v; } t;
        t.u[0] = f2bf(x0.x); t.u[1] = f2bf(x0.y); t.u[2] = f2bf(x0.z); t.u[3] = f2bf(x0.w);
        t.u[4] = f2bf(x1.x); t.u[5] = f2bf(x1.y); t.u[6] = f2bf(x1.z); t.u[7] = f2bf(x1.w);
        *(bf16x8*)&As[ch * 8] = t.v;
      } else {
        gload_lds16(Abf + (size_t)(m0 + r) * F_ + k0 + s * 8, &As[(i * 256 + wid * 64) * 8]);
      }
      gload_lds16(W + (size_t)(n0 + r) * F_ + k0 + s * 8, &Bs[(i * 256 + wid * 64) * 8]);
    }
    __syncthreads();

    bf16x8 af[4], bf[4];
#pragma unroll
    for (int m = 0; m < 4; ++m)
      af[m] = *(const bf16x8*)&As[(wr * 64 + m * 16 + lr) * 32 + lg * 8];
#pragma unroll
    for (int n = 0; n < 4; ++n)
      bf[n] = *(const bf16x8*)&Bs[(wc * 64 + n * 16 + lr) * 32 + lg * 8];
#pragma unroll
    for (int m = 0; m < 4; ++m)
#pragma unroll
      for (int n = 0; n < 4; ++n)
        acc[m][n] = __builtin_amdgcn_mfma_f32_16x16x32_bf16(af[m], bf[n], acc[m][n], 0, 0, 0);
    __syncthreads();
  }

  unsigned short* ob = OUT_F32 ? nullptr : outb + (size_t)p * BT_ * F_;
#pragma unroll
  for (int n = 0; n < 4; ++n) {
    const int col = n0 + wc * 64 + n * 16 + lr;
    const float bv = bias[col];
#pragma unroll
    for (int m = 0; m < 4; ++m) {
      const int rbase = m0 + wr * 64 + m * 16 + lg * 4;
#pragma unroll
      for (int j = 0; j < 4; ++j) {
        const float v = acc[m][n][j] + bv;
        if constexpr (OUT_F32) outf[(size_t)(rbase + j) * F_ + col] = v;
        else                   ob[(size_t)(rbase + j) * F_ + col] = f2bf(v);
      }
    }
  }
}

// ---------------- V transpose: (B,T,F)-per-head -> [BH][DK][T] ----------------
__global__ void transpose_v(const unsigned short* __restrict__ Vp, unsigned short* __restrict__ Vt) {
  const int bh = blockIdx.y, b = bh >> 3, h = bh & 7;
  const int t0 = blockIdx.x * 64;
  const int tid = threadIdx.x;
  __shared__ __align__(16) unsigned short tile[64][72];

#pragma unroll
  for (int i = 0; i < 2; ++i) {
    const int ch = i * 256 + tid;          // 512 chunks of 8
    const int t = ch >> 3, s = ch & 7;
    bf16x8 v = *(const bf16x8*)(Vp + (size_t)(b * T_ + t0 + t) * F_ + h * DK_ + s * 8);
    *(bf16x8*)&tile[t][s * 8] = v;
  }
  __syncthreads();
#pragma unroll
  for (int i = 0; i < 2; ++i) {
    const int ch = i * 256 + tid;
    const int d = ch >> 3, s = ch & 7;
    union { unsigned short u[8]; bf16x8 v; } r;
#pragma unroll
    for (int j = 0; j < 8; ++j) r.u[j] = tile[s * 8 + j][d];
    *(bf16x8*)(Vt + ((size_t)bh * DK_ + d) * T_ + t0 + s * 8) = r.v;
  }
}

// ---------------- flash attention ----------------
// block: 64 q-rows (4 waves x 16), KV tile = 64, double-buffered K/V staging.
// Exactly 40 KB LDS -> 4 blocks/CU (16 waves/CU).
__global__ __launch_bounds__(256, 4) void attn_kernel(
    const unsigned short* __restrict__ Qp,
    const unsigned short* __restrict__ Kp,
    const unsigned short* __restrict__ Vt,
    const float* __restrict__ maskf,
    unsigned short* __restrict__ X) {
  const int tid = threadIdx.x, wid = tid >> 6, lane = tid & 63;
  const int lr = lane & 15, lg = lane >> 4;
  const int bh = blockIdx.y, b = bh >> 3, h = bh & 7;
  const int wq0 = blockIdx.x * 64 + wid * 16;

  __shared__ __align__(16) unsigned short Ks[2][64 * 64];   // [kv][dk], 16B-slot XOR swizzle
  __shared__ __align__(16) unsigned short Vs[2][64 * 64];   // [d][kv], swizzled
  __shared__ __align__(16) unsigned short Ps[4][16 * 64];   // per-wave P, swizzled

  const float* mbase = maskf + b * T_ + lr;
  const float cLog2e = 0.18033688011112042f;  // (1/8) * log2(e)

  // Q fragments held in registers for the whole block
  bf16x8 qf[2];
#pragma unroll
  for (int kk = 0; kk < 2; ++kk)
    qf[kk] = *(const bf16x8*)(Qp + (size_t)(b * T_ + wq0 + lr) * F_ + h * DK_ + kk * 32 + lg * 8);

  float mrun[4], lrun[4];
  f32x4 ao[4] = {};
#pragma unroll
  for (int j = 0; j < 4; ++j) { mrun[j] = -1e30f; lrun[j] = 0.0f; }

  auto stage = [&](int buf, int kv0) {
#pragma unroll
    for (int i = 0; i < 2; ++i) {
      const int ch = i * 256 + tid;
      const int r = ch >> 3, s = ch & 7;
      gload_lds16(Kp + (size_t)(b * T_ + kv0 + r) * F_ + h * DK_ + ((s ^ (r & 7)) * 8),
                  &Ks[buf][(i * 256 + wid * 64) * 8]);
      gload_lds16(Vt + ((size_t)bh * DK_ + r) * T_ + kv0 + ((s ^ (r & 7)) * 8),
                  &Vs[buf][(i * 256 + wid * 64) * 8]);
    }
  };

  // prologue: stage tile 0, prefetch mask for tile 0
  stage(0, 0);
  float mf[4], mfN[4];
#pragma unroll
  for (int n = 0; n < 4; ++n) mf[n] = mbase[n * 16];
  __syncthreads();

  for (int t = 0; t < 32; ++t) {
    const int cur = t & 1;
    const int kv0 = t * 64;
    if (t < 31) {
      stage(cur ^ 1, kv0 + 64);
#pragma unroll
      for (int n = 0; n < 4; ++n) mfN[n] = mbase[kv0 + 64 + n * 16];
    }

    const unsigned short* pKs = Ks[cur];
    const unsigned short* pVs = Vs[cur];

    // S = Q K^T
    f32x4 sf[4] = {};
#pragma unroll
    for (int n = 0; n < 4; ++n) {
      const int col = n * 16 + lr;
#pragma unroll
      for (int kk = 0; kk < 2; ++kk) {
        bf16x8 kf = *(const bf16x8*)&pKs[col * 64 + ((((kk << 2) | lg) ^ (col & 7)) * 8)];
        sf[n] = __builtin_amdgcn_mfma_f32_16x16x32_bf16(qf[kk], kf, sf[n], 0, 0, 0);
      }
    }

    // scale (exp2 domain) + mask addend + row max
    float rmx[4];
#pragma unroll
    for (int j = 0; j < 4; ++j) {
      float mx = -__builtin_inff();
#pragma unroll
      for (int n = 0; n < 4; ++n) {
        const float s = fmaf(sf[n][j], cLog2e, mf[n]);
        sf[n][j] = s;
        mx = fmaxf(mx, s);
      }
      rmx[j] = mx;
    }
#pragma unroll
    for (int j = 0; j < 4; ++j)
#pragma unroll
      for (int d = 1; d < 16; d <<= 1)
        rmx[j] = fmaxf(rmx[j], __shfl_xor(rmx[j], d, 64));

    float alpha[4], rsum[4];
#pragma unroll
    for (int j = 0; j < 4; ++j) {
      const float mnew = fmaxf(mrun[j], rmx[j]);   // always finite
      alpha[j] = __builtin_amdgcn_exp2f(mrun[j] - mnew);
      mrun[j] = mnew;
      float rs = 0.0f;
#pragma unroll
      for (int n = 0; n < 4; ++n) {
        const float pv = __builtin_amdgcn_exp2f(sf[n][j] - mnew);  // -inf -> 0
        sf[n][j] = pv;
        rs += pv;
      }
      rsum[j] = rs;
    }
#pragma unroll
    for (int j = 0; j < 4; ++j) {
#pragma unroll
      for (int d = 1; d < 16; d <<= 1) rsum[j] += __shfl_xor(rsum[j], d, 64);
      lrun[j] = fmaf(lrun[j], alpha[j], rsum[j]);
    }
#pragma unroll
    for (int nd = 0; nd < 4; ++nd)
#pragma unroll
      for (int j = 0; j < 4; ++j) ao[nd][j] *= alpha[j];

    // P -> per-wave LDS (bf16, swizzled) to re-layout into MFMA A-fragments
#pragma unroll
    for (int n = 0; n < 4; ++n)
#pragma unroll
      for (int j = 0; j < 4; ++j) {
        const int r = lg * 4 + j;
        const int c = n * 16 + lr;
        Ps[wid][r * 64 + (((c >> 3) ^ (r & 7)) * 8) + (c & 7)] = f2bf(sf[n][j]);
      }
    asm volatile("s_waitcnt lgkmcnt(0)" ::: "memory");

    bf16x8 pf[2];
#pragma unroll
    for (int kk = 0; kk < 2; ++kk)
      pf[kk] = *(const bf16x8*)&Ps[wid][lr * 64 + ((((kk << 2) | lg) ^ (lr & 7)) * 8)];

    // O += P V
#pragma unroll
    for (int nd = 0; nd < 4; ++nd) {
      const int d = nd * 16 + lr;
#pragma unroll
      for (int kk = 0; kk < 2; ++kk) {
        bf16x8 vf = *(const bf16x8*)&pVs[d * 64 + ((((kk << 2) | lg) ^ (d & 7)) * 8)];
        ao[nd] = __builtin_amdgcn_mfma_f32_16x16x32_bf16(pf[kk], vf, ao[nd], 0, 0, 0);
      }
    }
    __syncthreads();   // drains vmcnt: stage(t+1) ready; buf[cur] reads all done

#pragma unroll
    for (int n = 0; n < 4; ++n) mf[n] = mfN[n];
  }

  // write X (bf16, (B,T,F) layout)
  float inv[4];
#pragma unroll
  for (int j = 0; j < 4; ++j) inv[j] = 1.0f / fmaxf(lrun[j], 1e-30f);
#pragma unroll
  for (int nd = 0; nd < 4; ++nd)
#pragma unroll
    for (int j = 0; j < 4; ++j) {
      const int row = wq0 + lg * 4 + j;
      const int col = h * DK_ + nd * 16 + lr;
      X[(size_t)(b * T_ + row) * F_ + col] = f2bf(ao[nd][j] * inv[j]);
    }
}

// ---------------- launcher ----------------
extern "C" void kernel_launch(void* const* d_in, const int* in_sizes, int n_in,
                              void* d_out, int out_size, void* d_ws, size_t ws_size,
                              hipStream_t stream) {
  const float* q  = (const float*)d_in[0];
  const float* k  = (const float*)d_in[1];
  const float* v  = (const float*)d_in[2];
  const int* mask = (const int*)d_in[3];
  const float* Wq = (const float*)d_in[4];
  const float* bq = (const float*)d_in[5];
  const float* Wk = (const float*)d_in[6];
  const float* bk = (const float*)d_in[7];
  const float* Wv = (const float*)d_in[8];
  const float* bv = (const float*)d_in[9];
  const float* Wo = (const float*)d_in[10];
  const float* bo = (const float*)d_in[11];
  float* out = (float*)d_out;

  unsigned short* ws = (unsigned short*)d_ws;
  unsigned short* wts  = ws;                               // 4*F*F           = 1,048,576
  unsigned short* proj = wts + (size_t)4 * F_ * F_;        // 3*BT*F (Q,K,V)  = 12,582,912
  unsigned short* vt   = proj + (size_t)3 * BT_ * F_;      // BT*F            = 4,194,304
  unsigned short* xbuf = vt + (size_t)BT_ * F_;            // BT*F            = 4,194,304
  float* maskf = (float*)(xbuf + (size_t)BT_ * F_);        // B*T floats      = 32 KB
  // total ~44 MB of d_ws

  convert_w<<<dim3(128, 5, 1), 256, 0, stream>>>(Wq, Wk, Wv, Wo, mask, wts, maskf);
  gemm_bt<true, false><<<dim3(64, 4, 3), 256, 0, stream>>>(
      q, k, v, nullptr, wts, bq, bk, bv, proj, nullptr);
  transpose_v<<<dim3(32, 32, 1), 256, 0, stream>>>(proj + (size_t)2 * BT_ * F_, vt);
  attn_kernel<<<dim3(32, 32, 1), 256, 0, stream>>>(
      proj, proj + (size_t)BT_ * F_, vt, maskf, xbuf);
  gemm_bt<false, true><<<dim3(64, 4, 1), 256, 0, stream>>>(
      nullptr, nullptr, nullptr, xbuf, wts + (size_t)3 * F_ * F_, bo, bo, bo, nullptr, out);
}

// Round 3
// 120.671 us; speedup vs baseline: 1.4277x; 1.3414x over previous
//
#include <hip/hip_runtime.h>
#include <hip/hip_bf16.h>
#include <stdint.h>

#define B_ 4
#define T_ 2048
#define F_ 512
#define H_ 8
#define DK_ 64
#define BT_ (B_*T_)   // 8192

typedef short bf16x8 __attribute__((ext_vector_type(8)));
typedef short s16x4 __attribute__((ext_vector_type(4)));
typedef float f32x4 __attribute__((ext_vector_type(4)));
typedef float f32x16 __attribute__((ext_vector_type(16)));

__device__ __forceinline__ unsigned short f2bf(float f) {
  union { float f; unsigned u; } v; v.f = f;
  return (unsigned short)((v.u + 0x7fffu + ((v.u >> 16) & 1u)) >> 16);
}

__device__ __forceinline__ unsigned pack2(float a, float b) {
  union { __hip_bfloat162 b2; unsigned u; } cv;
  cv.b2 = __hip_bfloat162(__float2bfloat16(a), __float2bfloat16(b));
  return cv.u;
}

__device__ __forceinline__ void gload_lds16(const void* g, void* l) {
  __builtin_amdgcn_global_load_lds((const __attribute__((address_space(1))) void*)g,
                                   (__attribute__((address_space(3))) void*)l, 16, 0, 0);
}

// ---------------- weight conversion fp32 -> bf16, plus mask -> float addend ----------------
__global__ void convert_w(const float* __restrict__ wq, const float* __restrict__ wk,
                          const float* __restrict__ wv, const float* __restrict__ wo,
                          const int* __restrict__ mask,
                          unsigned short* __restrict__ dst, float* __restrict__ maskf) {
  const int seg = blockIdx.y;
  if (seg == 4) {
    if (blockIdx.x < 4) {   // 4 blocks * 256 * 8 = 8192 = B*T exact
      const int idx = (blockIdx.x * 256 + threadIdx.x) * 8;
      int4 a = *(const int4*)(mask + idx);
      int4 b = *(const int4*)(mask + idx + 4);
      float4 fa, fb;
      fa.x = a.x ? 0.0f : -__builtin_inff(); fa.y = a.y ? 0.0f : -__builtin_inff();
      fa.z = a.z ? 0.0f : -__builtin_inff(); fa.w = a.w ? 0.0f : -__builtin_inff();
      fb.x = b.x ? 0.0f : -__builtin_inff(); fb.y = b.y ? 0.0f : -__builtin_inff();
      fb.z = b.z ? 0.0f : -__builtin_inff(); fb.w = b.w ? 0.0f : -__builtin_inff();
      *(float4*)(maskf + idx) = fa;
      *(float4*)(maskf + idx + 4) = fb;
    }
    return;
  }
  const float* src = seg == 0 ? wq : (seg == 1 ? wk : (seg == 2 ? wv : wo));
  unsigned short* out = dst + (size_t)seg * F_ * F_;
  const int idx = (blockIdx.x * 256 + threadIdx.x) * 8;   // 128 blocks * 256 * 8 = 262144 exact
  float4 a = *(const float4*)(src + idx);
  float4 b = *(const float4*)(src + idx + 4);
  union { unsigned short u[8]; bf16x8 v; } t;
  t.u[0] = f2bf(a.x); t.u[1] = f2bf(a.y); t.u[2] = f2bf(a.z); t.u[3] = f2bf(a.w);
  t.u[4] = f2bf(b.x); t.u[5] = f2bf(b.y); t.u[6] = f2bf(b.z); t.u[7] = f2bf(b.w);
  *(bf16x8*)(out + idx) = t.v;
}

// ---------------- GEMM: C = (A @ W^T + bias) * sc ----------------
template <bool A_F32, bool OUT_F32>
__global__ __launch_bounds__(256, 2) void gemm_bt(
    const float* __restrict__ af0, const float* __restrict__ af1, const float* __restrict__ af2,
    const unsigned short* __restrict__ Abf,
    const unsigned short* __restrict__ Wbase,
    const float* __restrict__ b0, const float* __restrict__ b1, const float* __restrict__ b2,
    unsigned short* __restrict__ outb, float* __restrict__ outf, float scale0) {
  const int p = blockIdx.z;
  const float* Af = (p == 0) ? af0 : (p == 1 ? af1 : af2);
  const unsigned short* W = Wbase + (size_t)p * F_ * F_;
  const float* bias = (p == 0) ? b0 : (p == 1 ? b1 : b2);
  const float sc = (p == 0) ? scale0 : 1.0f;

  const int tid = threadIdx.x;
  const int wid = tid >> 6, lane = tid & 63;
  const int lr = lane & 15, lg = lane >> 4;
  const int wr = wid >> 1, wc = wid & 1;
  const int m0 = blockIdx.x * 128, n0 = blockIdx.y * 128;

  __shared__ __align__(16) unsigned short As[128 * 32];
  __shared__ __align__(16) unsigned short Bs[128 * 32];

  f32x4 acc[4][4] = {};

  for (int k0 = 0; k0 < F_; k0 += 32) {
#pragma unroll
    for (int i = 0; i < 2; ++i) {
      const int ch = i * 256 + tid;
      const int r = ch >> 2, s = ch & 3;
      if constexpr (A_F32) {
        const float* src = Af + (size_t)(m0 + r) * F_ + k0 + s * 8;
        float4 x0 = *(const float4*)src;
        float4 x1 = *(const float4*)(src + 4);
        union { unsigned short u[8]; bf16x8 v; } t;
        t.u[0] = f2bf(x0.x); t.u[1] = f2bf(x0.y); t.u[2] = f2bf(x0.z); t.u[3] = f2bf(x0.w);
        t.u[4] = f2bf(x1.x); t.u[5] = f2bf(x1.y); t.u[6] = f2bf(x1.z); t.u[7] = f2bf(x1.w);
        *(bf16x8*)&As[ch * 8] = t.v;
      } else {
        gload_lds16(Abf + (size_t)(m0 + r) * F_ + k0 + s * 8, &As[(i * 256 + wid * 64) * 8]);
      }
      gload_lds16(W + (size_t)(n0 + r) * F_ + k0 + s * 8, &Bs[(i * 256 + wid * 64) * 8]);
    }
    __syncthreads();

    bf16x8 af[4], bf[4];
#pragma unroll
    for (int m = 0; m < 4; ++m)
      af[m] = *(const bf16x8*)&As[(wr * 64 + m * 16 + lr) * 32 + lg * 8];
#pragma unroll
    for (int n = 0; n < 4; ++n)
      bf[n] = *(const bf16x8*)&Bs[(wc * 64 + n * 16 + lr) * 32 + lg * 8];
#pragma unroll
    for (int m = 0; m < 4; ++m)
#pragma unroll
      for (int n = 0; n < 4; ++n)
        acc[m][n] = __builtin_amdgcn_mfma_f32_16x16x32_bf16(af[m], bf[n], acc[m][n], 0, 0, 0);
    __syncthreads();
  }

  unsigned short* ob = OUT_F32 ? nullptr : outb + (size_t)p * BT_ * F_;
#pragma unroll
  for (int n = 0; n < 4; ++n) {
    const int col = n0 + wc * 64 + n * 16 + lr;
    const float bv = bias[col];
#pragma unroll
    for (int m = 0; m < 4; ++m) {
      const int rbase = m0 + wr * 64 + m * 16 + lg * 4;
#pragma unroll
      for (int j = 0; j < 4; ++j) {
        const float v = (acc[m][n][j] + bv) * sc;
        if constexpr (OUT_F32) outf[(size_t)(rbase + j) * F_ + col] = v;
        else                   ob[(size_t)(rbase + j) * F_ + col] = f2bf(v);
      }
    }
  }
}

// ---------------- V transpose: (B,T,F)-per-head -> [BH][DK][T] ----------------
__global__ void transpose_v(const unsigned short* __restrict__ Vp, unsigned short* __restrict__ Vt) {
  const int bh = blockIdx.y, b = bh >> 3, h = bh & 7;
  const int t0 = blockIdx.x * 64;
  const int tid = threadIdx.x;
  __shared__ __align__(16) unsigned short tile[64][72];

#pragma unroll
  for (int i = 0; i < 2; ++i) {
    const int ch = i * 256 + tid;          // 512 chunks of 8
    const int t = ch >> 3, s = ch & 7;
    bf16x8 v = *(const bf16x8*)(Vp + (size_t)(b * T_ + t0 + t) * F_ + h * DK_ + s * 8);
    *(bf16x8*)&tile[t][s * 8] = v;
  }
  __syncthreads();
#pragma unroll
  for (int i = 0; i < 2; ++i) {
    const int ch = i * 256 + tid;
    const int d = ch >> 3, s = ch & 7;
    union { unsigned short u[8]; bf16x8 v; } r;
#pragma unroll
    for (int j = 0; j < 8; ++j) r.u[j] = tile[s * 8 + j][d];
    *(bf16x8*)(Vt + ((size_t)bh * DK_ + d) * T_ + t0 + s * 8) = r.v;
  }
}

// ---------------- flash attention, swapped-operand 32x32 ----------------
// 4 waves x 32 q-rows = 128 q/block; KV tile 64, double-buffered K/V^T/mask in LDS.
// S^T = mfma(K, Q): each lane owns ONE q-row (col = lane&31); softmax fully in-register
// (2 cross-lane shuffles for max/sum, 8 for the P half-exchange). O^T = mfma(V^T, P^T).
// Q is pre-scaled by 0.125*log2e (projection epilogue) -> exp2-domain softmax.
__global__ __launch_bounds__(256, 2) void attn_kernel(
    const unsigned short* __restrict__ Qp,
    const unsigned short* __restrict__ Kp,
    const unsigned short* __restrict__ Vt,
    const float* __restrict__ maskf,
    unsigned short* __restrict__ X) {
  const int tid = threadIdx.x, wid = tid >> 6, lane = tid & 63;
  const int la = lane & 31, hi = lane >> 5;
  const int bh = blockIdx.y, b = bh >> 3, h = bh & 7;
  const int wq0 = blockIdx.x * 128 + wid * 32;
  const int q = wq0 + la;

  __shared__ __align__(16) unsigned short Ks[2][64 * 64];  // [kv][dk], 16B-slot XOR swizzle
  __shared__ __align__(16) unsigned short Vs[2][64 * 64];  // [d][kv], swizzled
  __shared__ __align__(16) float Ms[2][256];               // mask addend (first 64 used)

  // Q B-fragments (held for whole block): B[k=kk*16+hi*8+e][col=la]
  bf16x8 qf[4];
#pragma unroll
  for (int kk = 0; kk < 4; ++kk)
    qf[kk] = *(const bf16x8*)(Qp + (size_t)(b * T_ + q) * F_ + h * DK_ + kk * 16 + hi * 8);

  f32x16 oacc[2] = {};
  float mrun = -1e30f, lrun = 0.0f;

  auto stage = [&](int buf, int kv0) {
#pragma unroll
    for (int i = 0; i < 2; ++i) {
      const int ch = i * 256 + tid;
      const int r = ch >> 3, s = ch & 7;
      gload_lds16(Kp + (size_t)(b * T_ + kv0 + r) * F_ + h * DK_ + ((s ^ (r & 7)) * 8),
                  &Ks[buf][(i * 256 + wid * 64) * 8]);
      gload_lds16(Vt + ((size_t)bh * DK_ + r) * T_ + kv0 + ((s ^ (r & 7)) * 8),
                  &Vs[buf][(i * 256 + wid * 64) * 8]);
    }
    if (wid == 0)
      gload_lds16(maskf + b * T_ + kv0 + lane * 4, &Ms[buf][0]);
  };

  stage(0, 0);
  __syncthreads();

  for (int t = 0; t < 32; ++t) {
    const int cur = t & 1;
    if (t < 31) stage(cur ^ 1, (t + 1) * 64);

    // K A-fragments: A[row=kv=n*32+la][k=kk*16+hi*8+e]
    bf16x8 kf0[4], kf1[4];
#pragma unroll
    for (int kk = 0; kk < 4; ++kk) {
      kf0[kk] = *(const bf16x8*)&Ks[cur][la * 64 + (((2 * kk + hi) ^ (la & 7)) * 8)];
      kf1[kk] = *(const bf16x8*)&Ks[cur][(32 + la) * 64 + (((2 * kk + hi) ^ (la & 7)) * 8)];
    }
    // mask addend, broadcast reads
    f32x4 mfv[2][4];
#pragma unroll
    for (int n = 0; n < 2; ++n)
#pragma unroll
      for (int g = 0; g < 4; ++g)
        mfv[n][g] = *(const f32x4*)&Ms[cur][n * 32 + 8 * g + 4 * hi];

    // S^T = K · Q^T  (col = q = la, row = kv = crow(reg,hi))
    f32x16 s0 = {}, s1 = {};
#pragma unroll
    for (int kk = 0; kk < 4; ++kk) {
      s0 = __builtin_amdgcn_mfma_f32_32x32x16_bf16(kf0[kk], qf[kk], s0, 0, 0, 0);
      s1 = __builtin_amdgcn_mfma_f32_32x32x16_bf16(kf1[kk], qf[kk], s1, 0, 0, 0);
    }

    // row max (raw/unmasked is a valid overestimate)
    float mx[16];
#pragma unroll
    for (int r = 0; r < 16; ++r) mx[r] = fmaxf(s0[r], s1[r]);
#pragma unroll
    for (int st = 8; st > 0; st >>= 1)
#pragma unroll
      for (int r = 0; r < st; ++r) mx[r] = fmaxf(mx[r], mx[r + st]);
    const float rmx = fmaxf(mx[0], __shfl_xor(mx[0], 32, 64));

    // defer-max (T13): rescale only when max grew beyond THR=8 (exp2 domain)
    if (!__all(rmx <= mrun + 8.0f)) {
      const float mnew = fmaxf(mrun, rmx);
      const float alpha = __builtin_amdgcn_exp2f(mrun - mnew);
      lrun *= alpha;
#pragma unroll
      for (int m = 0; m < 2; ++m)
#pragma unroll
        for (int r = 0; r < 16; ++r) oacc[m][r] *= alpha;
      mrun = mnew;
    }

    // P = exp2(S + mask - m)
    float p0[16], p1[16];
#pragma unroll
    for (int r = 0; r < 16; ++r) {
      p0[r] = __builtin_amdgcn_exp2f((s0[r] + mfv[0][r >> 2][r & 3]) - mrun);
      p1[r] = __builtin_amdgcn_exp2f((s1[r] + mfv[1][r >> 2][r & 3]) - mrun);
    }
    float sm[16];
#pragma unroll
    for (int r = 0; r < 16; ++r) sm[r] = p0[r] + p1[r];
#pragma unroll
    for (int st = 8; st > 0; st >>= 1)
#pragma unroll
      for (int r = 0; r < st; ++r) sm[r] += sm[r + st];
    lrun += sm[0] + __shfl_xor(sm[0], 32, 64);

    // pack P to bf16 pairs: pw[n][g][h] covers kv = n*32 + 8g + 4hi + {2h, 2h+1}
    unsigned pw[2][4][2];
#pragma unroll
    for (int g = 0; g < 4; ++g)
#pragma unroll
      for (int hh = 0; hh < 2; ++hh) {
        pw[0][g][hh] = pack2(p0[4 * g + 2 * hh], p0[4 * g + 2 * hh + 1]);
        pw[1][g][hh] = pack2(p1[4 * g + 2 * hh], p1[4 * g + 2 * hh + 1]);
      }
    // half-exchange with lane^32 partner -> B-fragment words
    unsigned lowr[2][2][2], uppr[2][2][2];
#pragma unroll
    for (int n = 0; n < 2; ++n)
#pragma unroll
      for (int gg = 0; gg < 2; ++gg)
#pragma unroll
        for (int hh = 0; hh < 2; ++hh) {
          const unsigned pwE = pw[n][2 * gg][hh], pwO = pw[n][2 * gg + 1][hh];
          const unsigned snd = hi ? pwE : pwO;
          const unsigned rcv = __shfl_xor(snd, 32, 64);
          lowr[n][gg][hh] = hi ? rcv : pwE;
          uppr[n][gg][hh] = hi ? pwO : rcv;
        }

    // O^T += V^T · P^T
#pragma unroll
    for (int kt = 0; kt < 4; ++kt) {
      const int n = kt >> 1, gg = kt & 1;
      union { unsigned w[4]; bf16x8 v; } pf;
      pf.w[0] = lowr[n][gg][0]; pf.w[1] = lowr[n][gg][1];
      pf.w[2] = uppr[n][gg][0]; pf.w[3] = uppr[n][gg][1];
#pragma unroll
      for (int m = 0; m < 2; ++m) {
        bf16x8 vfr = *(const bf16x8*)&Vs[cur][(m * 32 + la) * 64 + (((2 * kt + hi) ^ (la & 7)) * 8)];
        oacc[m] = __builtin_amdgcn_mfma_f32_32x32x16_bf16(vfr, pf.v, oacc[m], 0, 0, 0);
      }
    }
    __syncthreads();   // drains vmcnt: next tile staged; buf[cur] reads all done
  }

  // normalize + write X: thread owns q-row q, d = m*32 + 8g + 4hi + j
  const float inv = 1.0f / fmaxf(lrun, 1e-37f);
#pragma unroll
  for (int m = 0; m < 2; ++m)
#pragma unroll
    for (int g = 0; g < 4; ++g) {
      union { unsigned short u[4]; s16x4 v; } ov;
#pragma unroll
      for (int j = 0; j < 4; ++j) ov.u[j] = f2bf(oacc[m][4 * g + j] * inv);
      *(s16x4*)(X + (size_t)(b * T_ + q) * F_ + h * DK_ + m * 32 + 8 * g + 4 * hi) = ov.v;
    }
}

// ---------------- launcher ----------------
extern "C" void kernel_launch(void* const* d_in, const int* in_sizes, int n_in,
                              void* d_out, int out_size, void* d_ws, size_t ws_size,
                              hipStream_t stream) {
  const float* q  = (const float*)d_in[0];
  const float* k  = (const float*)d_in[1];
  const float* v  = (const float*)d_in[2];
  const int* mask = (const int*)d_in[3];
  const float* Wq = (const float*)d_in[4];
  const float* bq = (const float*)d_in[5];
  const float* Wk = (const float*)d_in[6];
  const float* bk = (const float*)d_in[7];
  const float* Wv = (const float*)d_in[8];
  const float* bv = (const float*)d_in[9];
  const float* Wo = (const float*)d_in[10];
  const float* bo = (const float*)d_in[11];
  float* out = (float*)d_out;

  unsigned short* ws = (unsigned short*)d_ws;
  unsigned short* wts  = ws;                               // 4*F*F           = 1,048,576
  unsigned short* proj = wts + (size_t)4 * F_ * F_;        // 3*BT*F (Q,K,V)
  unsigned short* vt   = proj + (size_t)3 * BT_ * F_;      // BT*F
  unsigned short* xbuf = vt + (size_t)BT_ * F_;            // BT*F
  float* maskf = (float*)(xbuf + (size_t)BT_ * F_);        // 8448 floats (B*T + 1KB slack)

  const float kQScale = 0.18033688011112042f;  // (1/sqrt(64)) * log2(e)

  convert_w<<<dim3(128, 5, 1), 256, 0, stream>>>(Wq, Wk, Wv, Wo, mask, wts, maskf);
  gemm_bt<true, false><<<dim3(64, 4, 3), 256, 0, stream>>>(
      q, k, v, nullptr, wts, bq, bk, bv, proj, nullptr, kQScale);
  transpose_v<<<dim3(32, 32, 1), 256, 0, stream>>>(proj + (size_t)2 * BT_ * F_, vt);
  attn_kernel<<<dim3(16, 32, 1), 256, 0, stream>>>(
      proj, proj + (size_t)BT_ * F_, vt, maskf, xbuf);
  gemm_bt<false, true><<<dim3(64, 4, 1), 256, 0, stream>>>(
      nullptr, nullptr, nullptr, xbuf, wts + (size_t)3 * F_ * F_, bo, bo, bo, nullptr, out, 1.0f);
}